// Round 7
// baseline (680.630 us; speedup 1.0000x reference)
//
#include <hip/hip_runtime.h>
#include <math.h>

// ============================================================================
// ROUND 7 — PHASE-ATTRIBUTION PROBE (sacrificial; r3 kernel is byte-identical
// otherwise). The kernel is IDEMPOTENT (reads only inputs, writes outputs
// deterministically, LDS re-zeroed per launch), so we launch it 3x on the
// same stream; each launch times a different phase via s_memrealtime and
// spins 10x that phase's duration at the end:
//   flag 1: prologue (gemm+zero+combine through its barrier)
//   flag 2: sum of paint regions (paint + post-paint barrier, x4)
//   flag 3: sum of epilogue calls (x4, store issue included)
// Decode from each dispatch's rocprof row: T_phase = (row_dur - 50)/10
// (kernel work = 50.2 us, measured r5 by two independent methods).
// Output exactness unchanged -> absmax must stay 0.0703125.
// ============================================================================

// Problem constants (from reference)
#define NB      2048        // batch
#define DIM     256         // input dim
#define SC6     192         // S*6 = 32 splines * 6 params
#define CV      128         // canvas size
#define NT      50          // samples along curve
#define NBPB    4           // batches per block (W amortization)
#define CWORDS  (CV * CV / 4)   // 4096 u8-packed words per canvas
// W_STAMP = -0.07, BG = 0.3, SCALE = 1e-4

#define LPV  (1591.9491530441301f)
#define ENV  (-1495.9491530441301f)

// Output layout (flat, return order): sketch | log_prob | entropy | sample
#define SKETCH_N   ((size_t)NB * CV * CV)     // 33,554,432
#define LP_OFF     (SKETCH_N)
#define ENT_OFF    (LP_OFF + NB)
#define SAMPLE_OFF (ENT_OFF + NB)

// Spin = SPIN_MULT x measured phase ticks, capped (RTC = 100 MHz).
#define SPIN_MULT 10ull
#define SPIN_CAP  100000ull   // <= 1 ms per dispatch

typedef float vfloat4 __attribute__((ext_vector_type(4)));

// Workgroup barrier waiting ONLY on LDS ops (lgkmcnt), not global stores.
__device__ __forceinline__ void barrier_lds_only() {
    asm volatile("s_waitcnt lgkmcnt(0)\n\ts_barrier" ::: "memory");
}

__device__ __forceinline__ unsigned long long rtclock() {
    asm volatile("" ::: "memory");
    unsigned long long t = __builtin_amdgcn_s_memrealtime();
    asm volatile("" ::: "memory");
    return t;
}

// Paint one batch's 32 splines into canvas cnv (u8-packed, per-row rotation).
// Expression order unchanged -> bit-identical coords vs the passing rounds.
__device__ __forceinline__ void do_paint(
    unsigned int* __restrict__ cnv,
    const double (* __restrict__ spb)[32],
    const double* __restrict__ cfa, const double* __restrict__ cfb,
    const double* __restrict__ cfc, int tid)
{
    const int s = tid & 31;
    const double P0x = spb[0][s], P0y = spb[1][s];
    const double P1x = spb[2][s], P1y = spb[3][s];
    const double P2x = spb[4][s], P2y = spb[5][s];

    for (int i = tid; i < 32 * NT; i += 512) {
        int kraw = i >> 5;                    // 0..49
        int k    = (kraw * 9) % 50;           // bijection, spreads t per wave
        double a  = cfa[k];
        double bq = cfb[k];
        double c  = cfc[k];
        double px = a * P0x + bq * P1x + c * P2x;  // same op order as prior
        double py = a * P0y + bq * P1y + c * P2y;  // passing rounds
        int cx = (int)rint(px);               // round-half-even == np.round
        int cy = (int)rint(py);

        // clipped y-triple -> u8 increments for 1-2 adjacent 4-px words
        int y0 = min(max(cy - 1, 0), CV - 1);
        int y1 = min(max(cy,     0), CV - 1);
        int y2 = min(max(cy + 1, 0), CV - 1);
        int cb = y0 >> 2;                     // base word-column (0..31)
        unsigned incA = 1u << ((y0 & 3) << 3);
        unsigned incB = 0u;
        unsigned i1 = 1u << ((y1 & 3) << 3);
        unsigned i2 = 1u << ((y2 & 3) << 3);
        if ((y1 >> 2) == cb) incA += i1; else incB += i1;
        if ((y2 >> 2) == cb) incA += i2; else incB += i2;

        int x0 = min(max(cx - 1, 0), CV - 1);
        int x1 = min(max(cx,     0), CV - 1);
        int x2 = min(max(cx + 1, 0), CV - 1);
        int rows[3] = {x0, x1, x2};
        #pragma unroll
        for (int r = 0; r < 3; ++r) {
            int xi = rows[r];
            int base = xi << 5;
            atomicAdd(&cnv[base + ((cb + xi) & 31)], incA);
            if (incB) atomicAdd(&cnv[base + ((cb + 1 + xi) & 31)], incB);
        }
    }
}

// Emit one batch's canvas (LUT + v==0 fast path, r3 code verbatim).
// Re-zeros the canvas in passing.
__device__ __forceinline__ void do_epilogue(
    unsigned int* __restrict__ cnv, float* __restrict__ outb,
    const float* __restrict__ lut, int tid)
{
    vfloat4* ob = (vfloat4*)outb;
    for (int w = tid; w < CWORDS; w += 512) {
        int xi  = w >> 5;                     // row
        int idx = (xi << 5) + (((w & 31) + xi) & 31);
        unsigned v = cnv[idx];
        cnv[idx] = 0u;
        vfloat4 r;
        if (v == 0u) {
            r.x = 0.3f; r.y = 0.3f; r.z = 0.3f; r.w = 0.3f;
        } else {
            r.x = lut[v & 255u];
            r.y = lut[(v >>  8) & 255u];
            r.z = lut[(v >> 16) & 255u];
            r.w = lut[v >> 24];
        }
        ob[w] = r;                            // cached store -> L2
    }
}

__global__ __launch_bounds__(512) void fused_kernel(
    const float* __restrict__ x, const float* __restrict__ W,
    const float* __restrict__ bias, float* __restrict__ out, int probe)
{
    __shared__ unsigned int cnt[2][CWORDS];       // 2 × 16 KB u8-packed
    __shared__ double sp[NBPB][6][32];            // SoA params*128, 4 batches
    __shared__ double cfa[NT], cfb[NT], cfc[NT];  // (1-t)^2, 2(1-t)t, t^2
    __shared__ float lut[256];                    // clip(0.3-0.07k,0,1)

    const int b0  = blockIdx.x * NBPB;
    const int tid = threadIdx.x;

    unsigned long long t_k0 = rtclock();          // PROBE: kernel entry

    if (tid < SC6) {
        // ---- gemm + sigmoid, 4 batches, W loaded once (f64 exact chains) ----
        const int j = tid;
        const float* xb = x + (size_t)b0 * DIM;   // wave-uniform -> s_load
        double a0 = 0.0, a1 = 0.0, a2 = 0.0, a3 = 0.0;
        #pragma unroll 8
        for (int d = 0; d < DIM; ++d) {
            double wd = (double)W[d * SC6 + j];
            a0 = fma((double)xb[d],           wd, a0);
            a1 = fma((double)xb[DIM + d],     wd, a1);
            a2 = fma((double)xb[2 * DIM + d], wd, a2);
            a3 = fma((double)xb[3 * DIM + d], wd, a3);
        }
        double bj = (double)bias[j];
        double s0 = 1.0 / (1.0 + exp(-(a0 + bj)));
        double s1 = 1.0 / (1.0 + exp(-(a1 + bj)));
        double s2 = 1.0 / (1.0 + exp(-(a2 + bj)));
        double s3 = 1.0 / (1.0 + exp(-(a3 + bj)));
        out[SAMPLE_OFF + (size_t)b0 * SC6 + j]       = (float)s0;
        out[SAMPLE_OFF + (size_t)(b0 + 1) * SC6 + j] = (float)s1;
        out[SAMPLE_OFF + (size_t)(b0 + 2) * SC6 + j] = (float)s2;
        out[SAMPLE_OFF + (size_t)(b0 + 3) * SC6 + j] = (float)s3;
        sp[0][j % 6][j / 6] = s0 * 128.0;         // CANVAS scale, SoA
        sp[1][j % 6][j / 6] = s1 * 128.0;
        sp[2][j % 6][j / 6] = s2 * 128.0;
        sp[3][j % 6][j / 6] = s3 * 128.0;
    } else {
        // ---- waves 3-7: zero BOTH canvases + coeff table + LUT + consts ----
        const int t2 = tid - SC6;                 // 0..319
        uint4* c4 = (uint4*)&cnt[0][0];           // 2048 uint4 words
        uint4 z = make_uint4(0u, 0u, 0u, 0u);
        for (int w = t2; w < 2048; w += 320) c4[w] = z;
        if (t2 < NT) {
            // np.linspace(0,1,50): t_k = k*fl64(1/49), endpoint forced to 1.0
            double t = (t2 == NT - 1) ? 1.0 : (double)t2 * (1.0 / 49.0);
            double u = 1.0 - t;
            cfa[t2] = u * u;                      // (1-t)**2
            cfb[t2] = (2.0 * u) * t;              // 2*(1-t)*t (ref assoc order)
            cfc[t2] = t * t;                      // t**2
        }
        if (t2 < 256) {
            lut[t2] = fminf(fmaxf(0.3f - 0.07f * (float)t2, 0.0f), 1.0f);
        }
        if (t2 >= 256 && t2 < 260) out[LP_OFF  + b0 + (t2 - 256)] = LPV;
        if (t2 >= 260 && t2 < 264) out[ENT_OFF + b0 + (t2 - 260)] = ENV;
    }
    barrier_lds_only();

    unsigned long long acc_pro = rtclock() - t_k0;   // PROBE: prologue done
    unsigned long long acc_pnt = 0, acc_epi = 0, t0;

    // ---- pipelined paint/epilogue over 4 batches, 2 canvases ----
    #pragma unroll
    for (int bb = 0; bb < NBPB; ++bb) {
        if (bb > 0) {
            t0 = rtclock();
            do_epilogue(cnt[(bb - 1) & 1],
                        out + (size_t)(b0 + bb - 1) * CV * CV, lut, tid);
            acc_epi += rtclock() - t0;
        }
        t0 = rtclock();
        do_paint(cnt[bb & 1], sp[bb], cfa, cfb, cfc, tid);
        barrier_lds_only();
        acc_pnt += rtclock() - t0;
    }
    t0 = rtclock();
    do_epilogue(cnt[(NBPB - 1) & 1],
                out + (size_t)(b0 + NBPB - 1) * CV * CV, lut, tid);
    acc_epi += rtclock() - t0;

    // PROBE: spin SPIN_MULT x the selected phase's measured ticks.
    {
        unsigned long long T = (probe == 1) ? acc_pro
                             : (probe == 2) ? acc_pnt
                                            : acc_epi;
        unsigned long long target = SPIN_MULT * T;
        if (target > SPIN_CAP) target = SPIN_CAP;
        unsigned long long s0 = __builtin_amdgcn_s_memrealtime();
        while (__builtin_amdgcn_s_memrealtime() - s0 < target) { }
    }
}

extern "C" void kernel_launch(void* const* d_in, const int* in_sizes, int n_in,
                              void* d_out, int out_size, void* d_ws, size_t ws_size,
                              hipStream_t stream) {
    const float* x    = (const float*)d_in[0];   // [2048, 256]
    const float* W    = (const float*)d_in[1];   // [256, 192]
    const float* bias = (const float*)d_in[2];   // [192]
    float* out = (float*)d_out;

    // Idempotent kernel: 3 sequential launches, each attributing one phase.
    // Order 1,2,3 so the GEMM probe (flag 1) sees the cold-cache state.
    fused_kernel<<<NB / NBPB, 512, 0, stream>>>(x, W, bias, out, 1);
    fused_kernel<<<NB / NBPB, 512, 0, stream>>>(x, W, bias, out, 2);
    fused_kernel<<<NB / NBPB, 512, 0, stream>>>(x, W, bias, out, 3);
}

// Round 8
// 158.359 us; speedup vs baseline: 4.2980x; 4.2980x over previous
//
#include <hip/hip_runtime.h>
#include <math.h>

// Problem constants (from reference)
#define NB      2048        // batch
#define DIM     256         // input dim
#define SC6     192         // S*6 = 32 splines * 6 params
#define CV      128         // canvas size
#define NT      50          // samples along curve
#define NBPB    4           // batches per block (W amortization)
#define CWORDS  (CV * CV / 4)   // 4096 u8-packed words per canvas
// W_STAMP = -0.07, BG = 0.3, SCALE = 1e-4

#define LPV  (1591.9491530441301f)
#define ENV  (-1495.9491530441301f)

// Output layout (flat, return order): sketch | log_prob | entropy | sample
#define SKETCH_N   ((size_t)NB * CV * CV)     // 33,554,432
#define LP_OFF     (SKETCH_N)
#define ENT_OFF    (LP_OFF + NB)
#define SAMPLE_OFF (ENT_OFF + NB)

typedef float vfloat4 __attribute__((ext_vector_type(4)));

// Workgroup barrier waiting ONLY on LDS ops (lgkmcnt), not global stores.
__device__ __forceinline__ void barrier_lds_only() {
    asm volatile("s_waitcnt lgkmcnt(0)\n\ts_barrier" ::: "memory");
}

// Paint one batch's 32 splines into canvas cnv (u8-packed, per-row rotation).
// Parameterized (t, stride) for wave-specialized calls; stride is always a
// multiple of 32 so s = t&31 stays loop-invariant. Expression order is
// r3-verbatim -> bit-identical coords; u32 atomics commute -> identical
// canvas counts regardless of thread mapping.
__device__ __forceinline__ void do_paint(
    unsigned int* __restrict__ cnv,
    const double (* __restrict__ spb)[32],
    const double* __restrict__ cfa, const double* __restrict__ cfb,
    const double* __restrict__ cfc, int t, int stride)
{
    const int s = t & 31;
    const double P0x = spb[0][s], P0y = spb[1][s];
    const double P1x = spb[2][s], P1y = spb[3][s];
    const double P2x = spb[4][s], P2y = spb[5][s];

    for (int i = t; i < 32 * NT; i += stride) {
        int kraw = i >> 5;                    // 0..49
        int k    = (kraw * 9) % 50;           // bijection, spreads t per wave
        double a  = cfa[k];
        double bq = cfb[k];
        double c  = cfc[k];
        double px = a * P0x + bq * P1x + c * P2x;  // same op order as prior
        double py = a * P0y + bq * P1y + c * P2y;  // passing rounds
        int cx = (int)rint(px);               // round-half-even == np.round
        int cy = (int)rint(py);

        // clipped y-triple -> u8 increments for 1-2 adjacent 4-px words
        int y0 = min(max(cy - 1, 0), CV - 1);
        int y1 = min(max(cy,     0), CV - 1);
        int y2 = min(max(cy + 1, 0), CV - 1);
        int cb = y0 >> 2;                     // base word-column (0..31)
        unsigned incA = 1u << ((y0 & 3) << 3);
        unsigned incB = 0u;
        unsigned i1 = 1u << ((y1 & 3) << 3);
        unsigned i2 = 1u << ((y2 & 3) << 3);
        if ((y1 >> 2) == cb) incA += i1; else incB += i1;
        if ((y2 >> 2) == cb) incA += i2; else incB += i2;

        int x0 = min(max(cx - 1, 0), CV - 1);
        int x1 = min(max(cx,     0), CV - 1);
        int x2 = min(max(cx + 1, 0), CV - 1);
        int rows[3] = {x0, x1, x2};
        #pragma unroll
        for (int r = 0; r < 3; ++r) {
            int xi = rows[r];
            int base = xi << 5;
            atomicAdd(&cnv[base + ((cb + xi) & 31)], incA);
            if (incB) atomicAdd(&cnv[base + ((cb + 1 + xi) & 31)], incB);
        }
    }
}

// Emit one batch's canvas (LUT + v==0 fast path, r3 arithmetic verbatim),
// parameterized (t, stride). Re-zeros the canvas in passing.
__device__ __forceinline__ void do_epilogue(
    unsigned int* __restrict__ cnv, float* __restrict__ outb,
    const float* __restrict__ lut, int t, int stride)
{
    vfloat4* ob = (vfloat4*)outb;
    for (int w = t; w < CWORDS; w += stride) {
        int xi  = w >> 5;                     // row
        int idx = (xi << 5) + (((w & 31) + xi) & 31);
        unsigned v = cnv[idx];
        cnv[idx] = 0u;
        vfloat4 r;
        if (v == 0u) {
            r.x = 0.3f; r.y = 0.3f; r.z = 0.3f; r.w = 0.3f;
        } else {
            r.x = lut[v & 255u];
            r.y = lut[(v >>  8) & 255u];
            r.z = lut[(v >> 16) & 255u];
            r.w = lut[v >> 24];
        }
        ob[w] = r;                            // cached store -> L2
    }
}

// ---------------------------------------------------------------------------
// v8 — WAVE-SPECIALIZED pipeline (from r7 phase probe: epilogue = 23 us AT
// the HBM write roofline; prologue+paint = 19 us of VALU with the write pipe
// idle; phases alternate globally because all waves/blocks are phase-locked).
//   prologue: gemm (waves 0-2) || zero canvases + tables (waves 3-7)
//   paint(0): all 8 waves (no prior epilogue to overlap)
//   bb=1..3:  waves 0-3 paint(bb)  ||  waves 4-7 epilogue(bb-1)   <- forced
//             concurrent VALU + store-issue, per iteration, by construction
//   tail:     epilogue(3) by all 8 waves
// Arithmetic bit-identical to r3 (atomics commute; only thread maps change).
// ---------------------------------------------------------------------------
__global__ __launch_bounds__(512) void fused_kernel(
    const float* __restrict__ x, const float* __restrict__ W,
    const float* __restrict__ bias, float* __restrict__ out)
{
    __shared__ unsigned int cnt[2][CWORDS];       // 2 × 16 KB u8-packed
    __shared__ double sp[NBPB][6][32];            // SoA params*128, 4 batches
    __shared__ double cfa[NT], cfb[NT], cfc[NT];  // (1-t)^2, 2(1-t)t, t^2
    __shared__ float lut[256];                    // clip(0.3-0.07k,0,1)

    const int b0  = blockIdx.x * NBPB;
    const int tid = threadIdx.x;

    if (tid < SC6) {
        // ---- gemm + sigmoid, 4 batches, W loaded once (f64 exact chains) ----
        const int j = tid;
        const float* xb = x + (size_t)b0 * DIM;   // wave-uniform -> s_load
        double a0 = 0.0, a1 = 0.0, a2 = 0.0, a3 = 0.0;
        #pragma unroll 8
        for (int d = 0; d < DIM; ++d) {
            double wd = (double)W[d * SC6 + j];
            a0 = fma((double)xb[d],           wd, a0);
            a1 = fma((double)xb[DIM + d],     wd, a1);
            a2 = fma((double)xb[2 * DIM + d], wd, a2);
            a3 = fma((double)xb[3 * DIM + d], wd, a3);
        }
        double bj = (double)bias[j];
        double s0 = 1.0 / (1.0 + exp(-(a0 + bj)));
        double s1 = 1.0 / (1.0 + exp(-(a1 + bj)));
        double s2 = 1.0 / (1.0 + exp(-(a2 + bj)));
        double s3 = 1.0 / (1.0 + exp(-(a3 + bj)));
        out[SAMPLE_OFF + (size_t)b0 * SC6 + j]       = (float)s0;
        out[SAMPLE_OFF + (size_t)(b0 + 1) * SC6 + j] = (float)s1;
        out[SAMPLE_OFF + (size_t)(b0 + 2) * SC6 + j] = (float)s2;
        out[SAMPLE_OFF + (size_t)(b0 + 3) * SC6 + j] = (float)s3;
        sp[0][j % 6][j / 6] = s0 * 128.0;         // CANVAS scale, SoA
        sp[1][j % 6][j / 6] = s1 * 128.0;
        sp[2][j % 6][j / 6] = s2 * 128.0;
        sp[3][j % 6][j / 6] = s3 * 128.0;
    } else {
        // ---- waves 3-7: zero BOTH canvases + coeff table + LUT + consts ----
        const int t2 = tid - SC6;                 // 0..319
        uint4* c4 = (uint4*)&cnt[0][0];           // 2048 uint4 words
        uint4 z = make_uint4(0u, 0u, 0u, 0u);
        for (int w = t2; w < 2048; w += 320) c4[w] = z;
        if (t2 < NT) {
            // np.linspace(0,1,50): t_k = k*fl64(1/49), endpoint forced to 1.0
            double t = (t2 == NT - 1) ? 1.0 : (double)t2 * (1.0 / 49.0);
            double u = 1.0 - t;
            cfa[t2] = u * u;                      // (1-t)**2
            cfb[t2] = (2.0 * u) * t;              // 2*(1-t)*t (ref assoc order)
            cfc[t2] = t * t;                      // t**2
        }
        if (t2 < 256) {
            lut[t2] = fminf(fmaxf(0.3f - 0.07f * (float)t2, 0.0f), 1.0f);
        }
        if (t2 >= 256 && t2 < 260) out[LP_OFF  + b0 + (t2 - 256)] = LPV;
        if (t2 >= 260 && t2 < 264) out[ENT_OFF + b0 + (t2 - 260)] = ENV;
    }
    barrier_lds_only();

    // ---- paint batch 0: all 8 waves (nothing to overlap yet) ----
    do_paint(cnt[0], sp[0], cfa, cfb, cfc, tid, 512);
    barrier_lds_only();

    // ---- specialized loop: paint(bb) [waves 0-3] || epilogue(bb-1) [4-7] --
    // Canvas rotation: paint(bb)->cnt[bb&1]; epilogue(bb-1) drains AND
    // re-zeros cnt[(bb-1)&1], which paint(bb+1) then reuses (barrier-ordered).
    #pragma unroll
    for (int bb = 1; bb < NBPB; ++bb) {
        if (tid < 256) {
            do_paint(cnt[bb & 1], sp[bb], cfa, cfb, cfc, tid, 256);
        } else {
            do_epilogue(cnt[(bb - 1) & 1],
                        out + (size_t)(b0 + bb - 1) * CV * CV,
                        lut, tid - 256, 256);
        }
        barrier_lds_only();
    }

    // ---- tail: epilogue of batch 3, all 8 waves ----
    do_epilogue(cnt[(NBPB - 1) & 1],
                out + (size_t)(b0 + NBPB - 1) * CV * CV, lut, tid, 512);
}

extern "C" void kernel_launch(void* const* d_in, const int* in_sizes, int n_in,
                              void* d_out, int out_size, void* d_ws, size_t ws_size,
                              hipStream_t stream) {
    const float* x    = (const float*)d_in[0];   // [2048, 256]
    const float* W    = (const float*)d_in[1];   // [256, 192]
    const float* bias = (const float*)d_in[2];   // [192]
    float* out = (float*)d_out;

    fused_kernel<<<NB / NBPB, 512, 0, stream>>>(x, W, bias, out);
}